// Round 1
// baseline (1852.291 us; speedup 1.0000x reference)
//
#include <hip/hip_runtime.h>
#include <hip/hip_cooperative_groups.h>
#include <hip/hip_bf16.h>
#include <math.h>

namespace cg = cooperative_groups;

// Problem constants
#define FPD 96      // frame size
#define DPD 28      // digit/kernel size
#define CPD 69      // FPD - DPD + 1
#define NPD 4761    // CPD*CPD
#define KKC 3       // K iterations
#define SBN 256     // S*B images
#define TT 8        // T
#define HD 512      // H
#define ZDD 2
#define KPAD 4768   // 149*32, padded K for MFMA GEMM
#define SPLITK 15
#define FRSH 104    // frame LDS row stride (halfs): 52 words, mod32=20 -> conflict-free
#define CVS 76      // cv slab row stride (floats): mod32=12 -> conflict-free

typedef __attribute__((ext_vector_type(8))) short bf16x8;
typedef __attribute__((ext_vector_type(4))) float f32x4;
typedef _Float16 half_t;
typedef __attribute__((ext_vector_type(2))) _Float16 half2_t;

__device__ __forceinline__ float bf2f_lo(unsigned int u) {
    union { unsigned int i; float f; } v; v.i = u << 16; return v.f;
}
__device__ __forceinline__ float bf2f_hi(unsigned int u) {
    union { unsigned int i; float f; } v; v.i = u & 0xffff0000u; return v.f;
}
__device__ __forceinline__ half2_t u2h(unsigned int u) {
    union { unsigned int i; half2_t h; } v; v.i = u; return v.h;
}

// Phase-overlaid LDS. Max member = conv (~106.4 KB) -> 1 block/CU.
union __align__(16) SharedU {
    struct {
        half_t fr[96 * FRSH];
        half_t kr[28 * 32];
        float  dg[784];
        float  cv[4][69 * CVS];
        float  red[32];
    } conv;
    struct {
        ushort As[4][64][56];
        ushort Bs[4][64][56];
    } gm;
    struct {
        ushort tile[4][64][65];
    } wp;
    struct {
        float hsh[HD];
        float h2[2][256];
        float res_sh[2][2];
    } mlp;
};

// ---------------------------------------------------------------------------
// One persistent cooperative kernel: wprep, then 3x (conv -> gemm -> mlp).
// 256 blocks x 1024 threads = 1 block/CU, all co-resident.
__global__ __launch_bounds__(1024, 4) void mega(
    const float* __restrict__ frames, const float* __restrict__ ck,
    const float* __restrict__ eps,
    const float* __restrict__ W1,  const float* __restrict__ b1,
    const float* __restrict__ Wm1, const float* __restrict__ bm1,
    const float* __restrict__ Wm2, const float* __restrict__ bm2,
    const float* __restrict__ Ws1, const float* __restrict__ bs1,
    const float* __restrict__ Ws2, const float* __restrict__ bs2,
    const int* __restrict__ tsp, float* __restrict__ out,
    float* __restrict__ frameL, float* __restrict__ Cpart,
    float* __restrict__ inv_denom, float* __restrict__ z_cur,
    ushort* __restrict__ e_buf, ushort* __restrict__ W1T,
    ushort* __restrict__ WhidT)
{
    cg::grid_group gg = cg::this_grid();
    __shared__ SharedU sh;
    const int t  = threadIdx.x;
    const int ib = blockIdx.x;

    // ===================== wprep: 4 x 256-thread groups =====================
    {
        const int g  = t >> 8;          // group 0..3
        const int tt = t & 255;
        const int ln = tt & 63;
        const int lr = tt >> 6;         // 0..3
        const int b  = ib * 4 + g;      // task id 0..1023 (664 used)
        ushort (*tile)[65] = sh.wp.tile[g];

        if (b < 600) {
            const int k0 = (b % 75) * 64;
            const int n0 = (b / 75) * 64;
            #pragma unroll
            for (int i = 0; i < 16; ++i) {
                int kk = k0 + lr + i * 4;
                float v = (kk < NPD) ? W1[(size_t)kk * HD + n0 + ln] : 0.f;
                __hip_bfloat16 h = __float2bfloat16(v);
                tile[lr + i * 4][ln] = *reinterpret_cast<ushort*>(&h);
            }
        } else if (b < 664) {
            const int bb = b - 600;
            const int i0 = (bb & 7) * 64;
            const int r0 = (bb >> 3) * 64;
            #pragma unroll
            for (int rep = 0; rep < 16; ++rep) {
                int i = i0 + lr + rep * 4;
                int r = r0 + ln;
                const float* srcp = (r >= 256) ? Ws1 : Wm1;
                float v = srcp[(size_t)i * 256 + (r & 255)];
                __hip_bfloat16 h = __float2bfloat16(v);
                tile[lr + rep * 4][ln] = *reinterpret_cast<ushort*>(&h);
            }
        }
        __syncthreads();
        if (b < 600) {
            const int k0 = (b % 75) * 64;
            const int n0 = (b / 75) * 64;
            #pragma unroll
            for (int i = 0; i < 16; ++i) {
                int nn = lr + i * 4;
                int kk = k0 + ln;
                if (kk < KPAD)
                    W1T[(size_t)(n0 + nn) * KPAD + kk] = tile[ln][nn];
            }
        } else if (b < 664) {
            const int bb = b - 600;
            const int i0 = (bb & 7) * 64;
            const int r0 = (bb >> 3) * 64;
            #pragma unroll
            for (int rep = 0; rep < 16; ++rep) {
                int r = r0 + lr + rep * 4;
                WhidT[(size_t)r * 512 + i0 + ln] = tile[ln][lr + rep * 4];
            }
        }
    }
    __threadfence();
    gg.sync();
    __threadfence();

    for (int k = 0; k < KKC; ++k) {
        // ===================== conv + recon-sub + softmax =====================
        {
            half_t* fr  = sh.conv.fr;
            half_t* kr  = sh.conv.kr;
            float*  dg  = sh.conv.dg;
            float*  red = sh.conv.red;

            if (t < 28 * 32) {
                int dy = t >> 5, dx = t & 31;
                float v = (dx < 28) ? ck[((size_t)ib * KKC + k) * 784 + dy * 28 + dx] : 0.f;
                kr[t] = (half_t)v;
            }
            if (k > 0 && t < 784) dg[t] = ck[((size_t)ib * KKC + (k - 1)) * 784 + t];
            float zx = 0.f, zy = 0.f;
            if (k > 0) { zx = z_cur[ib * 2]; zy = z_cur[ib * 2 + 1]; }
            __syncthreads();

            const float* src = (k < 2)
                ? frames + ((size_t)ib * TT + *tsp) * 9216
                : frameL + (size_t)ib * 9216;
            const float scale = 96.f / 28.f;
            for (int p = t; p < 9216; p += 1024) {
                int r = p / 96, c = p - r * 96;
                float val = src[p];
                if (k > 0) {
                    float oci = (2.f * r + 1.f) / 96.f - 1.f;
                    float ocj = (2.f * c + 1.f) / 96.f - 1.f;
                    float py = ((scale * (oci - zy) + 1.f) * 28.f - 1.f) * 0.5f;
                    float px = ((scale * (ocj - zx) + 1.f) * 28.f - 1.f) * 0.5f;
                    float py0f = floorf(py), px0f = floorf(px);
                    float fy = py - py0f, fx = px - px0f;
                    int y0 = (int)py0f, x0 = (int)px0f;
                    int y1 = y0 + 1, x1 = x0 + 1;
                    float wy0 = (y0 >= 0 && y0 < DPD) ? 1.f - fy : 0.f;
                    float wy1 = (y1 >= 0 && y1 < DPD) ? fy : 0.f;
                    float wx0 = (x0 >= 0 && x0 < DPD) ? 1.f - fx : 0.f;
                    float wx1 = (x1 >= 0 && x1 < DPD) ? fx : 0.f;
                    int y0c = min(max(y0, 0), DPD - 1), y1c = min(max(y1, 0), DPD - 1);
                    int x0c = min(max(x0, 0), DPD - 1), x1c = min(max(x1, 0), DPD - 1);
                    float tmp0 = wy0 * dg[y0c * DPD + x0c] + wy1 * dg[y1c * DPD + x0c];
                    float tmp1 = wy0 * dg[y0c * DPD + x1c] + wy1 * dg[y1c * DPD + x1c];
                    val -= wx0 * tmp0 + wx1 * tmp1;
                }
                fr[r * FRSH + c] = (half_t)val;
                if (k == 1) frameL[(size_t)ib * 9216 + p] = val;
            }
            if (t < 96 * 8) fr[(t >> 3) * FRSH + 96 + (t & 7)] = (half_t)0.f; // pad cols
            __syncthreads();

            if (t < 828) {
                const int q    = t / 207;
                const int rem  = t - q * 207;
                const int tile = rem / 69;
                const int oy   = rem - tile * 69;
                const int ox0  = tile * 24;
                const int dy0  = q * 7;

                float acc[24];
                #pragma unroll
                for (int j = 0; j < 24; ++j) acc[j] = 0.f;

                #pragma unroll 1
                for (int dd = 0; dd < 7; ++dd) {
                    const int dy = dy0 + dd;
                    const unsigned int* frow = (const unsigned int*)&fr[(oy + dy) * FRSH + ox0];
                    const unsigned int* krow = (const unsigned int*)&kr[dy * 32];
                    unsigned int W[28], K[16], V[25];
                    #pragma unroll
                    for (int u = 0; u < 7; ++u) {
                        uint4 v = *(const uint4*)(frow + 4 * u);
                        W[4*u] = v.x; W[4*u+1] = v.y; W[4*u+2] = v.z; W[4*u+3] = v.w;
                    }
                    #pragma unroll
                    for (int u = 0; u < 4; ++u) {
                        uint4 v = *(const uint4*)(krow + 4 * u);
                        K[4*u] = v.x; K[4*u+1] = v.y; K[4*u+2] = v.z; K[4*u+3] = v.w;
                    }
                    #pragma unroll
                    for (int i = 0; i < 25; ++i)
                        V[i] = (W[i] >> 16) | (W[i + 1] << 16);
                    #pragma unroll
                    for (int m = 0; m < 12; ++m) {
                        float ae = acc[2*m], ao = acc[2*m+1];
                        #pragma unroll
                        for (int i = 0; i < 14; ++i) {
                            ae = __builtin_amdgcn_fdot2(u2h(W[m + i]), u2h(K[i]), ae, false);
                            ao = __builtin_amdgcn_fdot2(u2h(V[m + i]), u2h(K[i]), ao, false);
                        }
                        acc[2*m] = ae; acc[2*m+1] = ao;
                    }
                }
                float* cvq = &sh.conv.cv[q][oy * CVS + ox0];
                #pragma unroll
                for (int u = 0; u < 6; ++u) {
                    float4 v = make_float4(acc[4*u], acc[4*u+1], acc[4*u+2], acc[4*u+3]);
                    *(float4*)(cvq + 4 * u) = v;
                }
            }
            __syncthreads();

            // merge quarters + block max
            float m = -INFINITY;
            for (int p = t; p < 69 * CVS; p += 1024) {
                int ox = p - (p / CVS) * CVS;
                if (ox < CPD) {
                    float v = sh.conv.cv[0][p] + sh.conv.cv[1][p]
                            + sh.conv.cv[2][p] + sh.conv.cv[3][p];
                    sh.conv.cv[0][p] = v;
                    m = fmaxf(m, v);
                }
            }
            #pragma unroll
            for (int off = 32; off > 0; off >>= 1) m = fmaxf(m, __shfl_down(m, off, 64));
            int lane = t & 63, wid = t >> 6;
            if (lane == 0) red[wid] = m;
            __syncthreads();
            m = red[0];
            #pragma unroll
            for (int i = 1; i < 16; ++i) m = fmaxf(m, red[i]);

            float s = 0.f;
            ushort* eo = e_buf + (size_t)ib * KPAD;
            for (int p = t; p < 69 * CVS; p += 1024) {
                int oy = p / CVS;
                int ox = p - oy * CVS;
                if (ox < CPD) {
                    float ev = __expf(sh.conv.cv[0][p] - m);
                    __hip_bfloat16 h = __float2bfloat16(ev);
                    eo[oy * CPD + ox] = *reinterpret_cast<ushort*>(&h);
                    s += ev;
                }
            }
            #pragma unroll
            for (int off = 32; off > 0; off >>= 1) s += __shfl_down(s, off, 64);
            if (lane == 0) red[16 + wid] = s;
            __syncthreads();
            if (t == 0) {
                float tot = 0.f;
                #pragma unroll
                for (int i = 0; i < 16; ++i) tot += red[16 + i];
                inv_denom[ib] = 1.0f / tot;
            }
            if (t < KPAD - NPD) eo[NPD + t] = 0;   // zero k-padding
        }
        __threadfence();
        gg.sync();
        __threadfence();

        // ===================== gemm1 (4 virtual 256-thread blocks) ============
        {
            const int g   = t >> 8;
            const int tt  = t & 255;
            const int vb  = ib * 4 + g;                 // 0..1023, 480 active
            const bool active = vb < 4 * 8 * SPLITK;
            const int m0  = (vb & 3) * 64;
            const int n0  = ((vb >> 2) & 7) * 64;
            const int z   = vb >> 5;
            const int step0 = z * 10;
            const int nstep = active ? min(10, 149 - step0) : 0;

            const int r  = tt >> 2;
            const int c  = tt & 3;
            const int l  = tt & 63;
            const int w  = tt >> 6;
            const int lm = l & 15;
            const int kb = l >> 4;

            ushort (*As)[56] = sh.gm.As[g];
            ushort (*Bs)[56] = sh.gm.Bs[g];

            f32x4 zero = {0.f, 0.f, 0.f, 0.f};
            f32x4 acc[4] = {zero, zero, zero, zero};

            const ushort* eA = e_buf + (size_t)(m0 + r) * KPAD + c * 8;
            const ushort* eB = W1T   + (size_t)(n0 + r) * KPAD + c * 8;

            float4 av = make_float4(0.f, 0.f, 0.f, 0.f), bv = av;
            if (active) {
                av = *(const float4*)(eA + step0 * 32);
                bv = *(const float4*)(eB + step0 * 32);
            }
            // uniform 10 iterations so all 4 groups hit the same barrier count
            for (int s = 0; s < 10; ++s) {
                bool act = s < nstep;
                if (act) {
                    *(float4*)&As[r][c * 8] = av;
                    *(float4*)&Bs[r][c * 8] = bv;
                }
                __syncthreads();
                if (act) {
                    if (s + 1 < nstep) {
                        int kn = (step0 + s + 1) * 32;
                        av = *(const float4*)(eA + kn);
                        bv = *(const float4*)(eB + kn);
                    }
                    bf16x8 a = *(const bf16x8*)&As[w * 16 + lm][kb * 8];
                    #pragma unroll
                    for (int j = 0; j < 4; ++j) {
                        bf16x8 b = *(const bf16x8*)&Bs[j * 16 + lm][kb * 8];
                        acc[j] = __builtin_amdgcn_mfma_f32_16x16x32_bf16(a, b, acc[j], 0, 0, 0);
                    }
                }
                __syncthreads();
            }

            if (active) {
                const int mrow = m0 + w * 16 + kb * 4;
                #pragma unroll
                for (int j = 0; j < 4; ++j) {
                    int n = n0 + j * 16 + lm;
                    #pragma unroll
                    for (int rg = 0; rg < 4; ++rg)
                        Cpart[((size_t)z * SBN + mrow + rg) * HD + n] = acc[j][rg];
                }
            }
        }
        __threadfence();
        gg.sync();
        __threadfence();

        // ===================== fused MLP (t < 512 active) =====================
        {
            if (t < HD) {
                float s = 0.f;
                #pragma unroll
                for (int z = 0; z < SPLITK; ++z)
                    s += Cpart[((size_t)z * SBN + ib) * HD + t];
                sh.mlp.hsh[t] = fmaxf(fmaf(s, inv_denom[ib], b1[t]), 0.f);
            }
            __syncthreads();

            if (t < 512) {
                int head = t >> 8, col = t & 255;
                const uint4* Wr = (const uint4*)(WhidT + (size_t)(head * 256 + col) * 512);
                float bias = head ? bs1[col] : bm1[col];
                float a = 0.f;
                #pragma unroll 8
                for (int u = 0; u < 64; ++u) {
                    uint4 wv = Wr[u];
                    const float* hp = &sh.mlp.hsh[u * 8];
                    a = fmaf(hp[0], bf2f_lo(wv.x), a);
                    a = fmaf(hp[1], bf2f_hi(wv.x), a);
                    a = fmaf(hp[2], bf2f_lo(wv.y), a);
                    a = fmaf(hp[3], bf2f_hi(wv.y), a);
                    a = fmaf(hp[4], bf2f_lo(wv.z), a);
                    a = fmaf(hp[5], bf2f_hi(wv.z), a);
                    a = fmaf(hp[6], bf2f_lo(wv.w), a);
                    a = fmaf(hp[7], bf2f_hi(wv.w), a);
                }
                sh.mlp.h2[head][col] = fmaxf(a + bias, 0.f);
            }
            __syncthreads();

            {
                int w = t >> 6, l = t & 63;
                if (w < 4) {
                    int zd = (w >> 1) & 1, head = w & 1;
                    const float* W2 = head ? Ws2 : Wm2;
                    float a = 0.f;
                    #pragma unroll
                    for (int u = 0; u < 4; ++u) {
                        int i = l + u * 64;
                        a = fmaf(sh.mlp.h2[head][i], W2[i * 2 + zd], a);
                    }
                    #pragma unroll
                    for (int off = 32; off > 0; off >>= 1) a += __shfl_down(a, off, 64);
                    if (l == 0) {
                        float r = head ? __expf(a + bs2[zd]) : tanhf(a + bm2[zd]);
                        sh.mlp.res_sh[zd][head] = r;
                    }
                }
            }
            __syncthreads();
            if (t < 2) {
                int zd = t;
                float mean = sh.mlp.res_sh[zd][0];
                float stdv = sh.mlp.res_sh[zd][1];
                float ev = eps[(size_t)ib * 6 + k * 2 + zd];
                float z = fmaf(stdv, ev, mean);
                int oidx = ib * 6 + k * 2 + zd;
                out[oidx]        = mean;   // q_mean
                out[1536 + oidx] = stdv;   // q_std
                out[3072 + oidx] = z;      // z_where
                z_cur[ib * 2 + zd] = z;
            }
        }
        // mlp -> next conv is block-local (block ib owns image ib everywhere):
        // device fence (L1 inval) + block barrier is sufficient.
        __threadfence();
        __syncthreads();
    }
}

// ---------------------------------------------------------------------------
extern "C" void kernel_launch(void* const* d_in, const int* in_sizes, int n_in,
                              void* d_out, int out_size, void* d_ws, size_t ws_size,
                              hipStream_t stream)
{
    const float* frames = (const float*)d_in[0];
    const float* ck     = (const float*)d_in[1];
    const float* eps    = (const float*)d_in[2];
    const float* W1     = (const float*)d_in[3];
    const float* b1     = (const float*)d_in[4];
    const float* Wm1    = (const float*)d_in[5];
    const float* bm1    = (const float*)d_in[6];
    const float* Wm2    = (const float*)d_in[7];
    const float* bm2    = (const float*)d_in[8];
    const float* Ws1    = (const float*)d_in[9];
    const float* bs1    = (const float*)d_in[10];
    const float* Ws2    = (const float*)d_in[11];
    const float* bs2    = (const float*)d_in[12];
    const int*   tsp    = (const int*)d_in[13];
    float* out = (float*)d_out;

    float* frameL  = (float*)d_ws;                   // 2359296 f
    float* Cpart   = frameL + 2359296;               // 15*256*512 = 1966080 f
    float* inv_den = Cpart + 1966080;                // 256 f
    float* z_cur   = inv_den + 256;                  // 512 f
    ushort* e_buf  = (ushort*)(z_cur + 512);         // 256*KPAD
    ushort* W1T    = e_buf + (size_t)SBN * KPAD;     // 512*KPAD
    ushort* WhidT  = W1T + (size_t)HD * KPAD;        // 512*512

    void* args[] = {
        (void*)&frames, (void*)&ck, (void*)&eps,
        (void*)&W1, (void*)&b1, (void*)&Wm1, (void*)&bm1,
        (void*)&Wm2, (void*)&bm2, (void*)&Ws1, (void*)&bs1,
        (void*)&Ws2, (void*)&bs2, (void*)&tsp, (void*)&out,
        (void*)&frameL, (void*)&Cpart, (void*)&inv_den, (void*)&z_cur,
        (void*)&e_buf, (void*)&W1T, (void*)&WhidT
    };
    hipLaunchCooperativeKernel((const void*)mega, dim3(256), dim3(1024),
                               args, 0, stream);
}

// Round 2
// 692.259 us; speedup vs baseline: 2.6757x; 2.6757x over previous
//
#include <hip/hip_runtime.h>
#include <hip/hip_cooperative_groups.h>
#include <hip/hip_bf16.h>
#include <math.h>

namespace cg = cooperative_groups;

// Problem constants
#define FPD 96      // frame size
#define DPD 28      // digit/kernel size
#define CPD 69      // FPD - DPD + 1
#define NPD 4761    // CPD*CPD
#define KKC 3       // K iterations
#define SBN 256     // S*B images
#define TT 8        // T
#define HD 512      // H
#define ZDD 2
#define KPAD 4768   // 149*32, padded K for MFMA GEMM
#define SPLITK 15
#define FRSH 104    // frame LDS row stride (halfs): 52 words, mod32=20 -> conflict-free
#define CVS 76      // cv slab row stride (floats): mod32=12 -> conflict-free

typedef __attribute__((ext_vector_type(8))) short bf16x8;
typedef __attribute__((ext_vector_type(4))) float f32x4;
typedef _Float16 half_t;
typedef __attribute__((ext_vector_type(2))) _Float16 half2_t;

__device__ __forceinline__ float bf2f_lo(unsigned int u) {
    union { unsigned int i; float f; } v; v.i = u << 16; return v.f;
}
__device__ __forceinline__ float bf2f_hi(unsigned int u) {
    union { unsigned int i; float f; } v; v.i = u & 0xffff0000u; return v.f;
}
__device__ __forceinline__ half2_t u2h(unsigned int u) {
    union { unsigned int i; half2_t h; } v; v.i = u; return v.h;
}

// Phase-overlaid LDS. Max member = conv (~106.4 KB) -> 1 block/CU.
union __align__(16) SharedU {
    struct {
        half_t fr[96 * FRSH];
        half_t kr[28 * 32];
        float  dg[784];
        float  cv[4][69 * CVS];
        float  red[32];
    } conv;
    struct {
        ushort As[4][64][56];
        ushort Bs[4][64][56];
    } gm;
    struct {
        ushort tile[4][64][65];
    } wp;
    struct {
        float hsh[HD];
        float h2[2][256];
        float res_sh[2][2];
    } mlp;
};

// ---------------------------------------------------------------------------
// One persistent cooperative kernel: wprep, then 3x (conv -> gemm -> mlp).
// 256 blocks x 1024 threads = 1 block/CU, all co-resident.
// waves_per_eu(4,4): LDS caps us at 1 block/CU (= 4 waves/EU) anyway; pinning
// max=4 stops the allocator squeezing to 64 VGPRs for an unreachable 8-wave
// occupancy step (round-1 showed VGPR_Count=64 -> degraded conv codegen).
__global__
__attribute__((amdgpu_flat_work_group_size(1024, 1024)))
__attribute__((amdgpu_waves_per_eu(4, 4)))
void mega(
    const float* __restrict__ frames, const float* __restrict__ ck,
    const float* __restrict__ eps,
    const float* __restrict__ W1,  const float* __restrict__ b1,
    const float* __restrict__ Wm1, const float* __restrict__ bm1,
    const float* __restrict__ Wm2, const float* __restrict__ bm2,
    const float* __restrict__ Ws1, const float* __restrict__ bs1,
    const float* __restrict__ Ws2, const float* __restrict__ bs2,
    const int* __restrict__ tsp, float* __restrict__ out,
    float* __restrict__ frameL, float* __restrict__ Cpart,
    float* __restrict__ inv_denom, float* __restrict__ z_cur,
    ushort* __restrict__ e_buf, ushort* __restrict__ W1T,
    ushort* __restrict__ WhidT)
{
    cg::grid_group gg = cg::this_grid();
    __shared__ SharedU sh;
    const int t  = threadIdx.x;
    const int ib = blockIdx.x;

    // ===================== wprep: 4 x 256-thread groups =====================
    {
        const int g  = t >> 8;          // group 0..3
        const int tt = t & 255;
        const int ln = tt & 63;
        const int lr = tt >> 6;         // 0..3
        const int b  = ib * 4 + g;      // task id 0..1023 (664 used)
        ushort (*tile)[65] = sh.wp.tile[g];

        if (b < 600) {
            const int k0 = (b % 75) * 64;
            const int n0 = (b / 75) * 64;
            #pragma unroll
            for (int i = 0; i < 16; ++i) {
                int kk = k0 + lr + i * 4;
                float v = (kk < NPD) ? W1[(size_t)kk * HD + n0 + ln] : 0.f;
                __hip_bfloat16 h = __float2bfloat16(v);
                tile[lr + i * 4][ln] = *reinterpret_cast<ushort*>(&h);
            }
        } else if (b < 664) {
            const int bb = b - 600;
            const int i0 = (bb & 7) * 64;
            const int r0 = (bb >> 3) * 64;
            #pragma unroll
            for (int rep = 0; rep < 16; ++rep) {
                int i = i0 + lr + rep * 4;
                int r = r0 + ln;
                const float* srcp = (r >= 256) ? Ws1 : Wm1;
                float v = srcp[(size_t)i * 256 + (r & 255)];
                __hip_bfloat16 h = __float2bfloat16(v);
                tile[lr + rep * 4][ln] = *reinterpret_cast<ushort*>(&h);
            }
        }
        __syncthreads();
        if (b < 600) {
            const int k0 = (b % 75) * 64;
            const int n0 = (b / 75) * 64;
            #pragma unroll
            for (int i = 0; i < 16; ++i) {
                int nn = lr + i * 4;
                int kk = k0 + ln;
                if (kk < KPAD)
                    W1T[(size_t)(n0 + nn) * KPAD + kk] = tile[ln][nn];
            }
        } else if (b < 664) {
            const int bb = b - 600;
            const int i0 = (bb & 7) * 64;
            const int r0 = (bb >> 3) * 64;
            #pragma unroll
            for (int rep = 0; rep < 16; ++rep) {
                int r = r0 + lr + rep * 4;
                WhidT[(size_t)r * 512 + i0 + ln] = tile[ln][lr + rep * 4];
            }
        }
    }
    gg.sync();

    for (int k = 0; k < KKC; ++k) {
        // ===================== conv + recon-sub + softmax =====================
        {
            half_t* fr  = sh.conv.fr;
            half_t* kr  = sh.conv.kr;
            float*  dg  = sh.conv.dg;
            float*  red = sh.conv.red;

            if (t < 28 * 32) {
                int dy = t >> 5, dx = t & 31;
                float v = (dx < 28) ? ck[((size_t)ib * KKC + k) * 784 + dy * 28 + dx] : 0.f;
                kr[t] = (half_t)v;
            }
            if (k > 0 && t < 784) dg[t] = ck[((size_t)ib * KKC + (k - 1)) * 784 + t];
            float zx = 0.f, zy = 0.f;
            if (k > 0) {
                zx = __hip_atomic_load(&z_cur[ib * 2], __ATOMIC_ACQUIRE,
                                       __HIP_MEMORY_SCOPE_AGENT);
                zy = __hip_atomic_load(&z_cur[ib * 2 + 1], __ATOMIC_ACQUIRE,
                                       __HIP_MEMORY_SCOPE_AGENT);
            }
            __syncthreads();

            const float* src = (k < 2)
                ? frames + ((size_t)ib * TT + *tsp) * 9216
                : frameL + (size_t)ib * 9216;
            const float scale = 96.f / 28.f;
            for (int p = t; p < 9216; p += 1024) {
                int r = p / 96, c = p - r * 96;
                float val = src[p];
                if (k > 0) {
                    float oci = (2.f * r + 1.f) / 96.f - 1.f;
                    float ocj = (2.f * c + 1.f) / 96.f - 1.f;
                    float py = ((scale * (oci - zy) + 1.f) * 28.f - 1.f) * 0.5f;
                    float px = ((scale * (ocj - zx) + 1.f) * 28.f - 1.f) * 0.5f;
                    float py0f = floorf(py), px0f = floorf(px);
                    float fy = py - py0f, fx = px - px0f;
                    int y0 = (int)py0f, x0 = (int)px0f;
                    int y1 = y0 + 1, x1 = x0 + 1;
                    float wy0 = (y0 >= 0 && y0 < DPD) ? 1.f - fy : 0.f;
                    float wy1 = (y1 >= 0 && y1 < DPD) ? fy : 0.f;
                    float wx0 = (x0 >= 0 && x0 < DPD) ? 1.f - fx : 0.f;
                    float wx1 = (x1 >= 0 && x1 < DPD) ? fx : 0.f;
                    int y0c = min(max(y0, 0), DPD - 1), y1c = min(max(y1, 0), DPD - 1);
                    int x0c = min(max(x0, 0), DPD - 1), x1c = min(max(x1, 0), DPD - 1);
                    float tmp0 = wy0 * dg[y0c * DPD + x0c] + wy1 * dg[y1c * DPD + x0c];
                    float tmp1 = wy0 * dg[y0c * DPD + x1c] + wy1 * dg[y1c * DPD + x1c];
                    val -= wx0 * tmp0 + wx1 * tmp1;
                }
                fr[r * FRSH + c] = (half_t)val;
                if (k == 1) frameL[(size_t)ib * 9216 + p] = val;
            }
            if (t < 96 * 8) fr[(t >> 3) * FRSH + 96 + (t & 7)] = (half_t)0.f; // pad cols
            __syncthreads();

            if (t < 828) {
                const int q    = t / 207;
                const int rem  = t - q * 207;
                const int tile = rem / 69;
                const int oy   = rem - tile * 69;
                const int ox0  = tile * 24;
                const int dy0  = q * 7;

                float acc[24];
                #pragma unroll
                for (int j = 0; j < 24; ++j) acc[j] = 0.f;

                #pragma unroll 1
                for (int dd = 0; dd < 7; ++dd) {
                    const int dy = dy0 + dd;
                    const unsigned int* frow = (const unsigned int*)&fr[(oy + dy) * FRSH + ox0];
                    const unsigned int* krow = (const unsigned int*)&kr[dy * 32];
                    unsigned int W[28], K[16], V[25];
                    #pragma unroll
                    for (int u = 0; u < 7; ++u) {
                        uint4 v = *(const uint4*)(frow + 4 * u);
                        W[4*u] = v.x; W[4*u+1] = v.y; W[4*u+2] = v.z; W[4*u+3] = v.w;
                    }
                    #pragma unroll
                    for (int u = 0; u < 4; ++u) {
                        uint4 v = *(const uint4*)(krow + 4 * u);
                        K[4*u] = v.x; K[4*u+1] = v.y; K[4*u+2] = v.z; K[4*u+3] = v.w;
                    }
                    #pragma unroll
                    for (int i = 0; i < 25; ++i)
                        V[i] = (W[i] >> 16) | (W[i + 1] << 16);
                    #pragma unroll
                    for (int m = 0; m < 12; ++m) {
                        float ae = acc[2*m], ao = acc[2*m+1];
                        #pragma unroll
                        for (int i = 0; i < 14; ++i) {
                            ae = __builtin_amdgcn_fdot2(u2h(W[m + i]), u2h(K[i]), ae, false);
                            ao = __builtin_amdgcn_fdot2(u2h(V[m + i]), u2h(K[i]), ao, false);
                        }
                        acc[2*m] = ae; acc[2*m+1] = ao;
                    }
                }
                float* cvq = &sh.conv.cv[q][oy * CVS + ox0];
                #pragma unroll
                for (int u = 0; u < 6; ++u) {
                    float4 v = make_float4(acc[4*u], acc[4*u+1], acc[4*u+2], acc[4*u+3]);
                    *(float4*)(cvq + 4 * u) = v;
                }
            }
            __syncthreads();

            // merge quarters + block max
            float m = -INFINITY;
            for (int p = t; p < 69 * CVS; p += 1024) {
                int ox = p - (p / CVS) * CVS;
                if (ox < CPD) {
                    float v = sh.conv.cv[0][p] + sh.conv.cv[1][p]
                            + sh.conv.cv[2][p] + sh.conv.cv[3][p];
                    sh.conv.cv[0][p] = v;
                    m = fmaxf(m, v);
                }
            }
            #pragma unroll
            for (int off = 32; off > 0; off >>= 1) m = fmaxf(m, __shfl_down(m, off, 64));
            int lane = t & 63, wid = t >> 6;
            if (lane == 0) red[wid] = m;
            __syncthreads();
            m = red[0];
            #pragma unroll
            for (int i = 1; i < 16; ++i) m = fmaxf(m, red[i]);

            float s = 0.f;
            ushort* eo = e_buf + (size_t)ib * KPAD;
            for (int p = t; p < 69 * CVS; p += 1024) {
                int oy = p / CVS;
                int ox = p - oy * CVS;
                if (ox < CPD) {
                    float ev = __expf(sh.conv.cv[0][p] - m);
                    __hip_bfloat16 h = __float2bfloat16(ev);
                    eo[oy * CPD + ox] = *reinterpret_cast<ushort*>(&h);
                    s += ev;
                }
            }
            #pragma unroll
            for (int off = 32; off > 0; off >>= 1) s += __shfl_down(s, off, 64);
            if (lane == 0) red[16 + wid] = s;
            __syncthreads();
            if (t == 0) {
                float tot = 0.f;
                #pragma unroll
                for (int i = 0; i < 16; ++i) tot += red[16 + i];
                inv_denom[ib] = 1.0f / tot;
            }
            if (t < KPAD - NPD) eo[NPD + t] = 0;   // zero k-padding
        }
        gg.sync();

        // ===================== gemm1 (4 virtual 256-thread blocks) ============
        {
            const int g   = t >> 8;
            const int tt  = t & 255;
            const int vb  = ib * 4 + g;                 // 0..1023, 480 active
            const bool active = vb < 4 * 8 * SPLITK;
            const int m0  = (vb & 3) * 64;
            const int n0  = ((vb >> 2) & 7) * 64;
            const int z   = vb >> 5;
            const int step0 = z * 10;
            const int nstep = active ? min(10, 149 - step0) : 0;

            const int r  = tt >> 2;
            const int c  = tt & 3;
            const int l  = tt & 63;
            const int w  = tt >> 6;
            const int lm = l & 15;
            const int kb = l >> 4;

            ushort (*As)[56] = sh.gm.As[g];
            ushort (*Bs)[56] = sh.gm.Bs[g];

            f32x4 zero = {0.f, 0.f, 0.f, 0.f};
            f32x4 acc[4] = {zero, zero, zero, zero};

            const ushort* eA = e_buf + (size_t)(m0 + r) * KPAD + c * 8;
            const ushort* eB = W1T   + (size_t)(n0 + r) * KPAD + c * 8;

            float4 av = make_float4(0.f, 0.f, 0.f, 0.f), bv = av;
            if (active) {
                av = *(const float4*)(eA + step0 * 32);
                bv = *(const float4*)(eB + step0 * 32);
            }
            // uniform 10 iterations so all 4 groups hit the same barrier count
            for (int s = 0; s < 10; ++s) {
                bool act = s < nstep;
                if (act) {
                    *(float4*)&As[r][c * 8] = av;
                    *(float4*)&Bs[r][c * 8] = bv;
                }
                __syncthreads();
                if (act) {
                    if (s + 1 < nstep) {
                        int kn = (step0 + s + 1) * 32;
                        av = *(const float4*)(eA + kn);
                        bv = *(const float4*)(eB + kn);
                    }
                    bf16x8 a = *(const bf16x8*)&As[w * 16 + lm][kb * 8];
                    #pragma unroll
                    for (int j = 0; j < 4; ++j) {
                        bf16x8 b = *(const bf16x8*)&Bs[j * 16 + lm][kb * 8];
                        acc[j] = __builtin_amdgcn_mfma_f32_16x16x32_bf16(a, b, acc[j], 0, 0, 0);
                    }
                }
                __syncthreads();
            }

            if (active) {
                const int mrow = m0 + w * 16 + kb * 4;
                #pragma unroll
                for (int j = 0; j < 4; ++j) {
                    int n = n0 + j * 16 + lm;
                    #pragma unroll
                    for (int rg = 0; rg < 4; ++rg)
                        Cpart[((size_t)z * SBN + mrow + rg) * HD + n] = acc[j][rg];
                }
            }
        }
        gg.sync();

        // ===================== fused MLP (t < 512 active) =====================
        {
            if (t < HD) {
                float s = 0.f;
                #pragma unroll
                for (int z = 0; z < SPLITK; ++z)
                    s += Cpart[((size_t)z * SBN + ib) * HD + t];
                sh.mlp.hsh[t] = fmaxf(fmaf(s, inv_denom[ib], b1[t]), 0.f);
            }
            __syncthreads();

            if (t < 512) {
                int head = t >> 8, col = t & 255;
                const uint4* Wr = (const uint4*)(WhidT + (size_t)(head * 256 + col) * 512);
                float bias = head ? bs1[col] : bm1[col];
                float a = 0.f;
                #pragma unroll 8
                for (int u = 0; u < 64; ++u) {
                    uint4 wv = Wr[u];
                    const float* hp = &sh.mlp.hsh[u * 8];
                    a = fmaf(hp[0], bf2f_lo(wv.x), a);
                    a = fmaf(hp[1], bf2f_hi(wv.x), a);
                    a = fmaf(hp[2], bf2f_lo(wv.y), a);
                    a = fmaf(hp[3], bf2f_hi(wv.y), a);
                    a = fmaf(hp[4], bf2f_lo(wv.z), a);
                    a = fmaf(hp[5], bf2f_hi(wv.z), a);
                    a = fmaf(hp[6], bf2f_lo(wv.w), a);
                    a = fmaf(hp[7], bf2f_hi(wv.w), a);
                }
                sh.mlp.h2[head][col] = fmaxf(a + bias, 0.f);
            }
            __syncthreads();

            {
                int w = t >> 6, l = t & 63;
                if (w < 4) {
                    int zd = (w >> 1) & 1, head = w & 1;
                    const float* W2 = head ? Ws2 : Wm2;
                    float a = 0.f;
                    #pragma unroll
                    for (int u = 0; u < 4; ++u) {
                        int i = l + u * 64;
                        a = fmaf(sh.mlp.h2[head][i], W2[i * 2 + zd], a);
                    }
                    #pragma unroll
                    for (int off = 32; off > 0; off >>= 1) a += __shfl_down(a, off, 64);
                    if (l == 0) {
                        float r = head ? __expf(a + bs2[zd]) : tanhf(a + bm2[zd]);
                        sh.mlp.res_sh[zd][head] = r;
                    }
                }
            }
            __syncthreads();
            if (t < 2) {
                int zd = t;
                float mean = sh.mlp.res_sh[zd][0];
                float stdv = sh.mlp.res_sh[zd][1];
                float ev = eps[(size_t)ib * 6 + k * 2 + zd];
                float z = fmaf(stdv, ev, mean);
                int oidx = ib * 6 + k * 2 + zd;
                out[oidx]        = mean;   // q_mean
                out[1536 + oidx] = stdv;   // q_std
                out[3072 + oidx] = z;      // z_where
                // block-local handoff to next conv: agent-scope atomic store
                // (sc1, bypasses L1) so the acquire-load in conv k+1 sees it.
                __hip_atomic_store(&z_cur[ib * 2 + zd], z, __ATOMIC_RELEASE,
                                   __HIP_MEMORY_SCOPE_AGENT);
            }
        }
        // mlp -> next conv is block-local (block ib owns image ib everywhere):
        // block barrier orders LDS-union reuse; z_cur handled via atomics.
        __syncthreads();
    }
}

// ---------------------------------------------------------------------------
extern "C" void kernel_launch(void* const* d_in, const int* in_sizes, int n_in,
                              void* d_out, int out_size, void* d_ws, size_t ws_size,
                              hipStream_t stream)
{
    const float* frames = (const float*)d_in[0];
    const float* ck     = (const float*)d_in[1];
    const float* eps    = (const float*)d_in[2];
    const float* W1     = (const float*)d_in[3];
    const float* b1     = (const float*)d_in[4];
    const float* Wm1    = (const float*)d_in[5];
    const float* bm1    = (const float*)d_in[6];
    const float* Wm2    = (const float*)d_in[7];
    const float* bm2    = (const float*)d_in[8];
    const float* Ws1    = (const float*)d_in[9];
    const float* bs1    = (const float*)d_in[10];
    const float* Ws2    = (const float*)d_in[11];
    const float* bs2    = (const float*)d_in[12];
    const int*   tsp    = (const int*)d_in[13];
    float* out = (float*)d_out;

    float* frameL  = (float*)d_ws;                   // 2359296 f
    float* Cpart   = frameL + 2359296;               // 15*256*512 = 1966080 f
    float* inv_den = Cpart + 1966080;                // 256 f
    float* z_cur   = inv_den + 256;                  // 512 f
    ushort* e_buf  = (ushort*)(z_cur + 512);         // 256*KPAD
    ushort* W1T    = e_buf + (size_t)SBN * KPAD;     // 512*KPAD
    ushort* WhidT  = W1T + (size_t)HD * KPAD;        // 512*512

    void* args[] = {
        (void*)&frames, (void*)&ck, (void*)&eps,
        (void*)&W1, (void*)&b1, (void*)&Wm1, (void*)&bm1,
        (void*)&Wm2, (void*)&bm2, (void*)&Ws1, (void*)&bs1,
        (void*)&Ws2, (void*)&bs2, (void*)&tsp, (void*)&out,
        (void*)&frameL, (void*)&Cpart, (void*)&inv_den, (void*)&z_cur,
        (void*)&e_buf, (void*)&W1T, (void*)&WhidT
    };
    hipLaunchCooperativeKernel((const void*)mega, dim3(256), dim3(1024),
                               args, 0, stream);
}

// Round 3
// 297.876 us; speedup vs baseline: 6.2183x; 2.3240x over previous
//
#include <hip/hip_runtime.h>
#include <hip/hip_bf16.h>
#include <math.h>

// Problem constants
#define FPD 96      // frame size
#define DPD 28      // digit/kernel size
#define CPD 69      // FPD - DPD + 1
#define NPD 4761    // CPD*CPD
#define KKC 3       // K iterations
#define SBN 256     // S*B images
#define TT 8        // T
#define HD 512      // H
#define ZDD 2
#define KPAD 4768   // 149*32, padded K for MFMA GEMM
#define SPLITK 15
#define FRSH 104    // frame LDS row stride (halfs): 52 words, mod32=20 -> conflict-free
#define CVS 76      // cv slab row stride (floats): mod32=12 -> conflict-free

typedef __attribute__((ext_vector_type(8))) short bf16x8;
typedef __attribute__((ext_vector_type(4))) float f32x4;
typedef _Float16 half_t;
typedef __attribute__((ext_vector_type(2))) _Float16 half2_t;

__device__ __forceinline__ float bf2f_lo(unsigned int u) {
    union { unsigned int i; float f; } v; v.i = u << 16; return v.f;
}
__device__ __forceinline__ float bf2f_hi(unsigned int u) {
    union { unsigned int i; float f; } v; v.i = u & 0xffff0000u; return v.f;
}
__device__ __forceinline__ half2_t u2h(unsigned int u) {
    union { unsigned int i; half2_t h; } v; v.i = u; return v.h;
}

// Conv-phase LDS block (~106.4 KB -> 1 block/CU for kernels containing it).
struct ConvLds {
    half_t fr[96 * FRSH];
    half_t kr[28 * 32];   // rows padded to 32 halfs
    float  dg[784];
    float  cv[4][69 * CVS];
    float  red[32];
};

struct MlpLds {
    float hsh[HD];
    float h2[2][256];
    float res_sh[2][2];
};

// ---------------------------------------------------------------------------
// Conv (f16 dot2) + fused recon-subtract + softmax-exp (bf16 out).
// 1024 threads, one image per block. Verified body (301 us baseline / mega).
__device__ __forceinline__ void conv_phase(
    ConvLds& L, int k, int ib, int t,
    const float* __restrict__ frames, const int* __restrict__ tsp,
    float* __restrict__ frameL, const float* __restrict__ ck,
    float zx, float zy,
    ushort* __restrict__ e_buf, float* __restrict__ inv_denom)
{
    half_t* fr  = L.fr;
    half_t* kr  = L.kr;
    float*  dg  = L.dg;
    float*  red = L.red;

    if (t < 28 * 32) {
        int dy = t >> 5, dx = t & 31;
        float v = (dx < 28) ? ck[((size_t)ib * KKC + k) * 784 + dy * 28 + dx] : 0.f;
        kr[t] = (half_t)v;
    }
    if (k > 0 && t < 784) dg[t] = ck[((size_t)ib * KKC + (k - 1)) * 784 + t];
    __syncthreads();

    const float* src = (k < 2)
        ? frames + ((size_t)ib * TT + *tsp) * 9216
        : frameL + (size_t)ib * 9216;
    const float scale = 96.f / 28.f;
    for (int p = t; p < 9216; p += 1024) {
        int r = p / 96, c = p - r * 96;
        float val = src[p];
        if (k > 0) {
            float oci = (2.f * r + 1.f) / 96.f - 1.f;
            float ocj = (2.f * c + 1.f) / 96.f - 1.f;
            float py = ((scale * (oci - zy) + 1.f) * 28.f - 1.f) * 0.5f;
            float px = ((scale * (ocj - zx) + 1.f) * 28.f - 1.f) * 0.5f;
            float py0f = floorf(py), px0f = floorf(px);
            float fy = py - py0f, fx = px - px0f;
            int y0 = (int)py0f, x0 = (int)px0f;
            int y1 = y0 + 1, x1 = x0 + 1;
            float wy0 = (y0 >= 0 && y0 < DPD) ? 1.f - fy : 0.f;
            float wy1 = (y1 >= 0 && y1 < DPD) ? fy : 0.f;
            float wx0 = (x0 >= 0 && x0 < DPD) ? 1.f - fx : 0.f;
            float wx1 = (x1 >= 0 && x1 < DPD) ? fx : 0.f;
            int y0c = min(max(y0, 0), DPD - 1), y1c = min(max(y1, 0), DPD - 1);
            int x0c = min(max(x0, 0), DPD - 1), x1c = min(max(x1, 0), DPD - 1);
            float tmp0 = wy0 * dg[y0c * DPD + x0c] + wy1 * dg[y1c * DPD + x0c];
            float tmp1 = wy0 * dg[y0c * DPD + x1c] + wy1 * dg[y1c * DPD + x1c];
            val -= wx0 * tmp0 + wx1 * tmp1;
        }
        fr[r * FRSH + c] = (half_t)val;
        if (k == 1) frameL[(size_t)ib * 9216 + p] = val;
    }
    if (t < 96 * 8) fr[(t >> 3) * FRSH + 96 + (t & 7)] = (half_t)0.f; // pad cols
    __syncthreads();

    if (t < 828) {
        const int q    = t / 207;
        const int rem  = t - q * 207;
        const int tile = rem / 69;
        const int oy   = rem - tile * 69;
        const int ox0  = tile * 24;
        const int dy0  = q * 7;

        float acc[24];
        #pragma unroll
        for (int j = 0; j < 24; ++j) acc[j] = 0.f;

        #pragma unroll 1
        for (int dd = 0; dd < 7; ++dd) {
            const int dy = dy0 + dd;
            const unsigned int* frow = (const unsigned int*)&fr[(oy + dy) * FRSH + ox0];
            const unsigned int* krow = (const unsigned int*)&kr[dy * 32];
            unsigned int W[28], K[16], V[25];
            #pragma unroll
            for (int u = 0; u < 7; ++u) {
                uint4 v = *(const uint4*)(frow + 4 * u);
                W[4*u] = v.x; W[4*u+1] = v.y; W[4*u+2] = v.z; W[4*u+3] = v.w;
            }
            #pragma unroll
            for (int u = 0; u < 4; ++u) {
                uint4 v = *(const uint4*)(krow + 4 * u);
                K[4*u] = v.x; K[4*u+1] = v.y; K[4*u+2] = v.z; K[4*u+3] = v.w;
            }
            #pragma unroll
            for (int i = 0; i < 25; ++i)
                V[i] = (W[i] >> 16) | (W[i + 1] << 16);
            #pragma unroll
            for (int m = 0; m < 12; ++m) {
                float ae = acc[2*m], ao = acc[2*m+1];
                #pragma unroll
                for (int i = 0; i < 14; ++i) {
                    ae = __builtin_amdgcn_fdot2(u2h(W[m + i]), u2h(K[i]), ae, false);
                    ao = __builtin_amdgcn_fdot2(u2h(V[m + i]), u2h(K[i]), ao, false);
                }
                acc[2*m] = ae; acc[2*m+1] = ao;
            }
        }
        float* cvq = &L.cv[q][oy * CVS + ox0];
        #pragma unroll
        for (int u = 0; u < 6; ++u) {
            float4 v = make_float4(acc[4*u], acc[4*u+1], acc[4*u+2], acc[4*u+3]);
            *(float4*)(cvq + 4 * u) = v;
        }
    }
    __syncthreads();

    // merge quarters + block max
    float m = -INFINITY;
    for (int p = t; p < 69 * CVS; p += 1024) {
        int ox = p - (p / CVS) * CVS;
        if (ox < CPD) {
            float v = L.cv[0][p] + L.cv[1][p] + L.cv[2][p] + L.cv[3][p];
            L.cv[0][p] = v;
            m = fmaxf(m, v);
        }
    }
    #pragma unroll
    for (int off = 32; off > 0; off >>= 1) m = fmaxf(m, __shfl_down(m, off, 64));
    int lane = t & 63, wid = t >> 6;
    if (lane == 0) red[wid] = m;
    __syncthreads();
    m = red[0];
    #pragma unroll
    for (int i = 1; i < 16; ++i) m = fmaxf(m, red[i]);

    float s = 0.f;
    ushort* eo = e_buf + (size_t)ib * KPAD;
    for (int p = t; p < 69 * CVS; p += 1024) {
        int oy = p / CVS;
        int ox = p - oy * CVS;
        if (ox < CPD) {
            float ev = __expf(L.cv[0][p] - m);
            __hip_bfloat16 h = __float2bfloat16(ev);
            eo[oy * CPD + ox] = *reinterpret_cast<ushort*>(&h);
            s += ev;
        }
    }
    #pragma unroll
    for (int off = 32; off > 0; off >>= 1) s += __shfl_down(s, off, 64);
    if (lane == 0) red[16 + wid] = s;
    __syncthreads();
    if (t == 0) {
        float tot = 0.f;
        #pragma unroll
        for (int i = 0; i < 16; ++i) tot += red[16 + i];
        inv_denom[ib] = 1.0f / tot;
    }
    if (t < KPAD - NPD) eo[NPD + t] = 0;   // zero k-padding
}

// ---------------------------------------------------------------------------
// Dispatch 1: conv(k=0) + weight-prep tail (4 x 256-thread groups; the same
// task split that ran verified inside the mega kernel).
__global__ __launch_bounds__(1024, 4) void conv0_wprep_kernel(
    const float* __restrict__ frames, const int* __restrict__ tsp,
    float* __restrict__ frameL, const float* __restrict__ ck,
    ushort* __restrict__ e_buf, float* __restrict__ inv_denom,
    const float* __restrict__ W1, const float* __restrict__ Wm1,
    const float* __restrict__ Ws1,
    ushort* __restrict__ W1T, ushort* __restrict__ WhidT)
{
    __shared__ union __align__(16) {
        ConvLds conv;
        ushort wp[4][64][65];
    } sh;
    const int t  = threadIdx.x;
    const int ib = blockIdx.x;

    conv_phase(sh.conv, 0, ib, t, frames, tsp, frameL, ck, 0.f, 0.f,
               e_buf, inv_denom);
    __syncthreads();   // conv LDS dead; reuse union for wprep

    {
        const int g  = t >> 8;          // group 0..3
        const int tt = t & 255;
        const int ln = tt & 63;
        const int lr = tt >> 6;         // 0..3
        const int b  = ib * 4 + g;      // task id, 664 used
        ushort (*tile)[65] = sh.wp[g];

        if (b < 600) {
            const int k0 = (b % 75) * 64;
            const int n0 = (b / 75) * 64;
            #pragma unroll
            for (int i = 0; i < 16; ++i) {
                int kk = k0 + lr + i * 4;
                float v = (kk < NPD) ? W1[(size_t)kk * HD + n0 + ln] : 0.f;
                __hip_bfloat16 h = __float2bfloat16(v);
                tile[lr + i * 4][ln] = *reinterpret_cast<ushort*>(&h);
            }
        } else if (b < 664) {
            const int bb = b - 600;
            const int i0 = (bb & 7) * 64;
            const int r0 = (bb >> 3) * 64;
            #pragma unroll
            for (int rep = 0; rep < 16; ++rep) {
                int i = i0 + lr + rep * 4;
                int r = r0 + ln;
                const float* srcp = (r >= 256) ? Ws1 : Wm1;
                float v = srcp[(size_t)i * 256 + (r & 255)];
                __hip_bfloat16 h = __float2bfloat16(v);
                tile[lr + rep * 4][ln] = *reinterpret_cast<ushort*>(&h);
            }
        }
        __syncthreads();
        if (b < 600) {
            const int k0 = (b % 75) * 64;
            const int n0 = (b / 75) * 64;
            #pragma unroll
            for (int i = 0; i < 16; ++i) {
                int nn = lr + i * 4;
                int kk = k0 + ln;
                if (kk < KPAD)
                    W1T[(size_t)(n0 + nn) * KPAD + kk] = tile[ln][nn];
            }
        } else if (b < 664) {
            const int bb = b - 600;
            const int i0 = (bb & 7) * 64;
            const int r0 = (bb >> 3) * 64;
            #pragma unroll
            for (int rep = 0; rep < 16; ++rep) {
                int r = r0 + lr + rep * 4;
                WhidT[(size_t)r * 512 + i0 + ln] = tile[ln][lr + rep * 4];
            }
        }
    }
}

// ---------------------------------------------------------------------------
// Cpart[z] = E(256xKPAD bf16) @ W1T^T (KPADx512 bf16), split-K=15, MFMA.
// Verbatim from the 301 us baseline.
__global__ __launch_bounds__(256) void gemm1_mfma(
    const ushort* __restrict__ E, const ushort* __restrict__ W1T,
    float* __restrict__ Cpart)
{
    __shared__ __align__(16) ushort As[64][56];   // [m][k]
    __shared__ __align__(16) ushort Bs[64][56];   // [n][k]

    const int t  = threadIdx.x;
    const int m0 = blockIdx.x * 64;   // 4
    const int n0 = blockIdx.y * 64;   // 8
    const int z  = blockIdx.z;        // 15
    const int step0 = z * 10;
    const int nstep = min(10, 149 - step0);   // z=14 -> 9

    const int r = t >> 2;             // 0..63
    const int c = t & 3;              // 0..3
    const int l = t & 63;
    const int w = t >> 6;             // wave 0..3
    const int lm = l & 15;
    const int kb = l >> 4;            // 0..3

    f32x4 zero = {0.f, 0.f, 0.f, 0.f};
    f32x4 acc[4] = {zero, zero, zero, zero};

    const ushort* eA = E   + (size_t)(m0 + r) * KPAD + c * 8;
    const ushort* eB = W1T + (size_t)(n0 + r) * KPAD + c * 8;

    int k0 = step0 * 32;
    float4 av = *(const float4*)(eA + k0);
    float4 bv = *(const float4*)(eB + k0);

    for (int s = 0; s < nstep; ++s) {
        *(float4*)&As[r][c * 8] = av;
        *(float4*)&Bs[r][c * 8] = bv;
        __syncthreads();
        if (s + 1 < nstep) {
            int kn = (step0 + s + 1) * 32;
            av = *(const float4*)(eA + kn);
            bv = *(const float4*)(eB + kn);
        }
        bf16x8 a = *(const bf16x8*)&As[w * 16 + lm][kb * 8];
        #pragma unroll
        for (int j = 0; j < 4; ++j) {
            bf16x8 b = *(const bf16x8*)&Bs[j * 16 + lm][kb * 8];
            acc[j] = __builtin_amdgcn_mfma_f32_16x16x32_bf16(a, b, acc[j], 0, 0, 0);
        }
        __syncthreads();
    }

    // C/D layout: col = lane&15 (n), row = (lane>>4)*4 + reg (m)
    const int mrow = m0 + w * 16 + kb * 4;
    #pragma unroll
    for (int j = 0; j < 4; ++j) {
        int n = n0 + j * 16 + lm;
        #pragma unroll
        for (int rg = 0; rg < 4; ++rg)
            Cpart[((size_t)z * SBN + mrow + rg) * HD + n] = acc[j][rg];
    }
}

// ---------------------------------------------------------------------------
// MLP phase (t < 512 active; verified body). Returns z via z_keep LDS.
__device__ __forceinline__ void mlp_phase(
    MlpLds& L, int km, int ib, int t,
    const float* __restrict__ Cpart, const float* __restrict__ inv_denom,
    const float* __restrict__ b1, const ushort* __restrict__ WhidT,
    const float* __restrict__ bm1, const float* __restrict__ bs1,
    const float* __restrict__ Wm2, const float* __restrict__ bm2,
    const float* __restrict__ Ws2, const float* __restrict__ bs2,
    const float* __restrict__ eps, float* __restrict__ out,
    float* z_keep)
{
    if (t < HD) {
        float s = 0.f;
        #pragma unroll
        for (int z = 0; z < SPLITK; ++z)
            s += Cpart[((size_t)z * SBN + ib) * HD + t];
        L.hsh[t] = fmaxf(fmaf(s, inv_denom[ib], b1[t]), 0.f);
    }
    __syncthreads();

    if (t < 512) {
        int head = t >> 8, col = t & 255;
        const uint4* Wr = (const uint4*)(WhidT + (size_t)(head * 256 + col) * 512);
        float bias = head ? bs1[col] : bm1[col];
        float a = 0.f;
        #pragma unroll 8
        for (int u = 0; u < 64; ++u) {
            uint4 wv = Wr[u];
            const float* hp = &L.hsh[u * 8];
            a = fmaf(hp[0], bf2f_lo(wv.x), a);
            a = fmaf(hp[1], bf2f_hi(wv.x), a);
            a = fmaf(hp[2], bf2f_lo(wv.y), a);
            a = fmaf(hp[3], bf2f_hi(wv.y), a);
            a = fmaf(hp[4], bf2f_lo(wv.z), a);
            a = fmaf(hp[5], bf2f_hi(wv.z), a);
            a = fmaf(hp[6], bf2f_lo(wv.w), a);
            a = fmaf(hp[7], bf2f_hi(wv.w), a);
        }
        L.h2[head][col] = fmaxf(a + bias, 0.f);
    }
    __syncthreads();

    {
        int w = t >> 6, l = t & 63;
        if (w < 4) {
            int zd = (w >> 1) & 1, head = w & 1;
            const float* W2 = head ? Ws2 : Wm2;
            float a = 0.f;
            #pragma unroll
            for (int u = 0; u < 4; ++u) {
                int i = l + u * 64;
                a = fmaf(L.h2[head][i], W2[i * 2 + zd], a);
            }
            #pragma unroll
            for (int off = 32; off > 0; off >>= 1) a += __shfl_down(a, off, 64);
            if (l == 0) {
                float r = head ? __expf(a + bs2[zd]) : tanhf(a + bm2[zd]);
                L.res_sh[zd][head] = r;
            }
        }
    }
    __syncthreads();
    if (t < 2) {
        int zd = t;
        float mean = L.res_sh[zd][0];
        float stdv = L.res_sh[zd][1];
        float ev = eps[(size_t)ib * 6 + km * 2 + zd];
        float z = fmaf(stdv, ev, mean);
        int oidx = ib * 6 + km * 2 + zd;
        out[oidx]        = mean;   // q_mean
        out[1536 + oidx] = stdv;   // q_std
        out[3072 + oidx] = z;      // z_where
        z_keep[zd] = z;            // block-local handoff to fused conv
    }
}

// ---------------------------------------------------------------------------
// Dispatch 3/5: mlp(km) + conv(km+1), fully block-local fusion (block ib owns
// image ib in both phases; z passes through LDS, no global round-trip).
__global__ __launch_bounds__(1024, 4) void mlp_conv_kernel(
    const float* __restrict__ Cpart, const float* __restrict__ inv_denom,
    const float* __restrict__ b1, const ushort* __restrict__ WhidT,
    const float* __restrict__ bm1, const float* __restrict__ bs1,
    const float* __restrict__ Wm2, const float* __restrict__ bm2,
    const float* __restrict__ Ws2, const float* __restrict__ bs2,
    const float* __restrict__ eps, float* __restrict__ out,
    const float* __restrict__ frames, const int* __restrict__ tsp,
    float* __restrict__ frameL, const float* __restrict__ ck,
    ushort* __restrict__ e_buf, int km)
{
    __shared__ union __align__(16) {
        ConvLds conv;
        MlpLds  mlp;
    } sh;
    __shared__ float z_keep[2];
    const int t  = threadIdx.x;
    const int ib = blockIdx.x;

    mlp_phase(sh.mlp, km, ib, t, Cpart, inv_denom, b1, WhidT,
              bm1, bs1, Wm2, bm2, Ws2, bs2, eps, out, z_keep);
    __syncthreads();   // mlp LDS dead; z_keep visible to all

    float zx = z_keep[0], zy = z_keep[1];
    conv_phase(sh.conv, km + 1, ib, t, frames, tsp, frameL, ck, zx, zy,
               e_buf, (float*)inv_denom);
}

// ---------------------------------------------------------------------------
// Dispatch 7: final mlp (km=2), standalone. Verbatim baseline shape.
__global__ __launch_bounds__(512) void mlp_final_kernel(
    const float* __restrict__ Cpart, const float* __restrict__ inv_denom,
    const float* __restrict__ b1, const ushort* __restrict__ WhidT,
    const float* __restrict__ bm1, const float* __restrict__ bs1,
    const float* __restrict__ Wm2, const float* __restrict__ bm2,
    const float* __restrict__ Ws2, const float* __restrict__ bs2,
    const float* __restrict__ eps, float* __restrict__ out)
{
    __shared__ MlpLds L;
    __shared__ float z_keep[2];
    mlp_phase(L, 2, blockIdx.x, threadIdx.x, Cpart, inv_denom, b1, WhidT,
              bm1, bs1, Wm2, bm2, Ws2, bs2, eps, out, z_keep);
}

// ---------------------------------------------------------------------------
extern "C" void kernel_launch(void* const* d_in, const int* in_sizes, int n_in,
                              void* d_out, int out_size, void* d_ws, size_t ws_size,
                              hipStream_t stream)
{
    const float* frames = (const float*)d_in[0];
    const float* ck     = (const float*)d_in[1];
    const float* eps    = (const float*)d_in[2];
    const float* W1     = (const float*)d_in[3];
    const float* b1     = (const float*)d_in[4];
    const float* Wm1    = (const float*)d_in[5];
    const float* bm1    = (const float*)d_in[6];
    const float* Wm2    = (const float*)d_in[7];
    const float* bm2    = (const float*)d_in[8];
    const float* Ws1    = (const float*)d_in[9];
    const float* bs1    = (const float*)d_in[10];
    const float* Ws2    = (const float*)d_in[11];
    const float* bs2    = (const float*)d_in[12];
    const int*   tsp    = (const int*)d_in[13];
    float* out = (float*)d_out;

    float* frameL  = (float*)d_ws;                   // 2359296 f
    float* Cpart   = frameL + 2359296;               // 15*256*512 = 1966080 f
    float* inv_den = Cpart + 1966080;                // 256 f
    ushort* e_buf  = (ushort*)(inv_den + 256);       // 256*KPAD
    ushort* W1T    = e_buf + (size_t)SBN * KPAD;     // 512*KPAD
    ushort* WhidT  = W1T + (size_t)HD * KPAD;        // 512*512

    // D1: conv k=0 (+ wprep tail)
    conv0_wprep_kernel<<<256, 1024, 0, stream>>>(
        frames, tsp, frameL, ck, e_buf, inv_den, W1, Wm1, Ws1, W1T, WhidT);
    // D2: gemm k=0
    gemm1_mfma<<<dim3(4, 8, SPLITK), 256, 0, stream>>>(e_buf, W1T, Cpart);
    // D3: mlp k=0 + conv k=1
    mlp_conv_kernel<<<256, 1024, 0, stream>>>(
        Cpart, inv_den, b1, WhidT, bm1, bs1, Wm2, bm2, Ws2, bs2,
        eps, out, frames, tsp, frameL, ck, e_buf, 0);
    // D4: gemm k=1
    gemm1_mfma<<<dim3(4, 8, SPLITK), 256, 0, stream>>>(e_buf, W1T, Cpart);
    // D5: mlp k=1 + conv k=2
    mlp_conv_kernel<<<256, 1024, 0, stream>>>(
        Cpart, inv_den, b1, WhidT, bm1, bs1, Wm2, bm2, Ws2, bs2,
        eps, out, frames, tsp, frameL, ck, e_buf, 1);
    // D6: gemm k=2
    gemm1_mfma<<<dim3(4, 8, SPLITK), 256, 0, stream>>>(e_buf, W1T, Cpart);
    // D7: mlp k=2
    mlp_final_kernel<<<256, 512, 0, stream>>>(
        Cpart, inv_den, b1, WhidT, bm1, bs1, Wm2, bm2, Ws2, bs2, eps, out);
}